// Round 5
// baseline (171.277 us; speedup 1.0000x reference)
//
#include <hip/hip_runtime.h>

#define NB 32
#define LL 2048
#define CH 512
#define BQ 512
#define HH 1024
#define LDA 520   // LDS row stride (bf16): +8 pad -> measured 0 bank conflicts (r3/r4)

typedef __attribute__((ext_vector_type(8))) short bf16x8;
typedef __attribute__((ext_vector_type(16))) float f32x16;

__device__ __forceinline__ unsigned short f2bf(float x) {
  unsigned int u = __float_as_uint(x);
  u += 0x7FFFu + ((u >> 16) & 1u);   // round-to-nearest-even
  return (unsigned short)(u >> 16);
}

__device__ __forceinline__ unsigned int cvt_pk_bf16(float a, float b) {
  unsigned int r;
  asm("v_cvt_pk_bf16_f32 %0, %1, %2" : "=v"(r) : "v"(a), "v"(b));
  return r;   // lo16 = bf16(a), hi16 = bf16(b)
}

__device__ __forceinline__ float fast_tanh(float x) {
  // tanh(x) = 1 - 2/(exp2(2*log2e*x)+1); saturates correctly at +-inf
  float e = __builtin_amdgcn_exp2f(x * 2.885390081777927f);
  return 1.0f - 2.0f * __builtin_amdgcn_rcpf(e + 1.0f);
}

// ---------------- res_qc[b][h] = query[b,:]·Wq[h,:] + bc[h] ----------------
__global__ __launch_bounds__(256) void k_resqc(const float* __restrict__ query,
                                               const float* __restrict__ Wq,
                                               const float* __restrict__ bc,
                                               float* __restrict__ resqc) {
  int gid = blockIdx.x * 256 + threadIdx.x;   // 32768
  int b = gid >> 10, h = gid & 1023;
  const float4* q4 = (const float4*)(query + (size_t)b * BQ);
  const float4* w4 = (const float4*)(Wq + (size_t)h * BQ);
  float acc = 0.f;
#pragma unroll 4
  for (int i = 0; i < BQ / 4; ++i) {
    float4 a = q4[i], w = w4[i];
    acc += a.x * w.x + a.y * w.y + a.z * w.z + a.w * w.w;
  }
  resqc[gid] = acc + bc[h];
}

// ---------------- Wc f32 -> bf16, packed in MFMA B-fragment order ----------------
// wcbp[cg][ks][lane][8] : lane=(lo,hi) gets Wc[cg*32+lo][hi*8 + ks*16 .. +8]
__global__ __launch_bounds__(256) void k_pack_wc(const float* __restrict__ Wc,
                                                 unsigned short* __restrict__ wcbp) {
  int gid = blockIdx.x * 256 + threadIdx.x;   // 65536 = 32 cg * 32 ks * 64 lanes
  int lane = gid & 63, ks = (gid >> 6) & 31, cg = gid >> 11;
  int lo = lane & 31, hi = lane >> 5;
  const float4* s = (const float4*)(Wc + (size_t)(cg * 32 + lo) * CH + hi * 8 + ks * 16);
  float4 v0 = s[0], v1 = s[1];
  union { unsigned short s[8]; uint4 u; } p;
  p.s[0] = f2bf(v0.x); p.s[1] = f2bf(v0.y); p.s[2] = f2bf(v0.z); p.s[3] = f2bf(v0.w);
  p.s[4] = f2bf(v1.x); p.s[5] = f2bf(v1.y); p.s[6] = f2bf(v1.z); p.s[7] = f2bf(v1.w);
  ((uint4*)wcbp)[gid] = p.u;
}

// ---------------- main: logits[b][l] = sum_h Wo[h]*tanh(resqc[b][h] + ctx[b,l,:]·Wc[h,:])
// 256 persistent blocks (1/CU) x 1024 threads (16 waves). Each block: 4 l-tiles
// of 64 rows x full H=1024 (wave w -> cols [64w,64w+64)). A tile double-buffered
// in LDS; next tile's loads issued before the epilogue (latency hidden under it).
__global__ __launch_bounds__(1024, 4) void k_logits(const float* __restrict__ ctx,
                                                    const unsigned short* __restrict__ wcbp,
                                                    const float* __restrict__ resqc,
                                                    const float* __restrict__ Wo,
                                                    float* __restrict__ logits) {
  __shared__ unsigned short Alds[2][64 * LDA];   // 2 x 66560 B
  __shared__ float lsum4[4][64];

  const int t = threadIdx.x;
  const int bid = blockIdx.x;       // 256 blocks x 4 tiles
  const int g0 = bid * 4;

  if (t < 256) lsum4[t >> 6][t & 63] = 0.f;

  // prologue: stage tile g0 into buf 0 (64x512 f32 -> bf16, 8 float4/thread)
  {
    int b = g0 >> 5, row0 = (g0 & 31) << 6;
    const float4* src = (const float4*)(ctx + ((size_t)(b * LL + row0)) * CH);
#pragma unroll
    for (int i = 0; i < 8; ++i) {
      int f = i * 1024 + t;
      int r = f >> 7, c4 = f & 127;
      float4 v = src[f];
      uint2 w;
      w.x = cvt_pk_bf16(v.x, v.y);
      w.y = cvt_pk_bf16(v.z, v.w);
      *(uint2*)(Alds[0] + r * LDA + c4 * 4) = w;
    }
  }
  __syncthreads();

  const int wave = t >> 6, lane = t & 63;
  const int lo = lane & 31, hi = lane >> 5;
  const int n0 = wave * 64;          // this wave's 64 cols (full H across 16 waves)
  const uint4* bp0 = (const uint4*)wcbp + (size_t)(wave * 2) * 32 * 64 + lane;
  const uint4* bp1 = bp0 + 32 * 64;
  const float wA = Wo[n0 + lo], wB = Wo[n0 + 32 + lo];

  for (int tt = 0; tt < 4; ++tt) {
    const int g = g0 + tt;
    const int b = g >> 5, row0 = (g & 31) << 6;
    const int cur = tt & 1;
    const char* a0b = (const char*)(Alds[cur]) + lo * (LDA * 2) + hi * 16;
    const char* a1b = a0b + 32 * (LDA * 2);

    f32x16 acc00 = {0,0,0,0,0,0,0,0,0,0,0,0,0,0,0,0};
    f32x16 acc01 = {0,0,0,0,0,0,0,0,0,0,0,0,0,0,0,0};
    f32x16 acc10 = {0,0,0,0,0,0,0,0,0,0,0,0,0,0,0,0};
    f32x16 acc11 = {0,0,0,0,0,0,0,0,0,0,0,0,0,0,0,0};
#pragma unroll 8
    for (int ks = 0; ks < 32; ++ks) {           // K = 512/16
      uint4 ub0 = bp0[ks * 64];
      uint4 ub1 = bp1[ks * 64];
      bf16x8 fa0 = *(const bf16x8*)(a0b + ks * 32);
      bf16x8 fa1 = *(const bf16x8*)(a1b + ks * 32);
      bf16x8 fb0, fb1;
      __builtin_memcpy(&fb0, &ub0, 16);
      __builtin_memcpy(&fb1, &ub1, 16);
      acc00 = __builtin_amdgcn_mfma_f32_32x32x16_bf16(fa0, fb0, acc00, 0, 0, 0);
      acc01 = __builtin_amdgcn_mfma_f32_32x32x16_bf16(fa0, fb1, acc01, 0, 0, 0);
      acc10 = __builtin_amdgcn_mfma_f32_32x32x16_bf16(fa1, fb0, acc10, 0, 0, 0);
      acc11 = __builtin_amdgcn_mfma_f32_32x32x16_bf16(fa1, fb1, acc11, 0, 0, 0);
    }

    // issue next tile's stage loads now; HBM latency hides under the epilogue
    float4 sv[8];
    if (tt < 3) {
      int gn = g + 1;
      int nb = gn >> 5, nrow0 = (gn & 31) << 6;
      const float4* srcn = (const float4*)(ctx + ((size_t)(nb * LL + nrow0)) * CH);
#pragma unroll
      for (int i = 0; i < 8; ++i) sv[i] = srcn[i * 1024 + t];
    }

    // epilogue: tanh + Wo-weighted sum -> 32 partials per lane
    float qA = resqc[b * HH + n0 + lo], qB = resqc[b * HH + n0 + 32 + lo];
    float v[32];
#pragma unroll
    for (int r = 0; r < 16; ++r) {
      v[r]      = wA * fast_tanh(acc00[r] + qA) + wB * fast_tanh(acc01[r] + qB);
      v[16 + r] = wA * fast_tanh(acc10[r] + qA) + wB * fast_tanh(acc11[r] + qB);
    }
    // transpose-reduce: 31 shfl instead of 160. After 5 levels lane lo holds the
    // full 32-lane sum of value index lo (bit of index set iff lo&s took upper half).
#pragma unroll
    for (int s = 16; s >= 1; s >>= 1) {
#pragma unroll
      for (int i = 0; i < s; ++i) {
        float a = v[i], c = v[i + s];
        float keep = (lo & s) ? c : a;
        float send = (lo & s) ? a : c;
        v[i] = keep + __shfl_xor(send, s, 64);
      }
    }
    int rr = lo & 15;
    int row = ((lo < 16) ? 0 : 32) + (rr & 3) + 8 * (rr >> 2) + 4 * hi;  // C/D row map
    atomicAdd(&lsum4[tt][row], v[0]);

    // write staged next tile into the other buffer
    if (tt < 3) {
#pragma unroll
      for (int i = 0; i < 8; ++i) {
        int f = i * 1024 + t;
        int r = f >> 7, c4 = f & 127;
        uint2 w;
        w.x = cvt_pk_bf16(sv[i].x, sv[i].y);
        w.y = cvt_pk_bf16(sv[i].z, sv[i].w);
        *(uint2*)(Alds[cur ^ 1] + r * LDA + c4 * 4) = w;
      }
    }
    __syncthreads();
    if (t < 64) logits[(size_t)b * LL + row0 + t] = lsum4[tt][t];
  }
}

// ---------------- weights: mask*exp(logit+bo), normalize over L ----------------
__global__ __launch_bounds__(256) void k_weights(const float* __restrict__ mask,
                                                 const float* __restrict__ bo,
                                                 const float* __restrict__ logit,
                                                 float* __restrict__ wout) {
  __shared__ float red[4];
  int b = blockIdx.x, t = threadIdx.x;
  float bov = bo[0];
  float w[8];
  float s = 0.f;
#pragma unroll
  for (int i = 0; i < 8; ++i) {
    int l = t + 256 * i;
    float e = mask[b * LL + l] * __expf(logit[b * LL + l] + bov);
    w[i] = e; s += e;
  }
#pragma unroll
  for (int m = 32; m >= 1; m >>= 1) s += __shfl_xor(s, m, 64);
  int wave = t >> 6, lane = t & 63;
  if (lane == 0) red[wave] = s;
  __syncthreads();
  float inv = 1.0f / (red[0] + red[1] + red[2] + red[3] + 1e-5f);
#pragma unroll
  for (int i = 0; i < 8; ++i) wout[b * LL + t + 256 * i] = w[i] * inv;
}

// ---------------- output[b][c] = sum_l weights[b][l] * ctx[b][l][c] ----------------
__global__ __launch_bounds__(256) void k_output(const float* __restrict__ ctx,
                                                const float* __restrict__ weights,
                                                float* __restrict__ out) {
  __shared__ float wl[128];
  int bid = blockIdx.x;            // 512 = 32 b * 16 chunks
  int b = bid >> 4, chunk = bid & 15;
  int t = threadIdx.x;
  int l0 = chunk * 128;
  if (t < 128) wl[t] = weights[b * LL + l0 + t];
  __syncthreads();
  const float2* c2 = (const float2*)(ctx + ((size_t)(b * LL + l0)) * CH) + t;
  float ax = 0.f, ay = 0.f;
#pragma unroll 4
  for (int l = 0; l < 128; ++l) {
    float wv = wl[l];
    float2 v = c2[(size_t)l * (CH / 2)];
    ax += wv * v.x; ay += wv * v.y;
  }
  atomicAdd(&out[b * CH + 2 * t], ax);
  atomicAdd(&out[b * CH + 2 * t + 1], ay);
}

extern "C" void kernel_launch(void* const* d_in, const int* in_sizes, int n_in,
                              void* d_out, int out_size, void* d_ws, size_t ws_size,
                              hipStream_t stream) {
  const float* query = (const float*)d_in[0];
  const float* ctx   = (const float*)d_in[1];
  const float* mask  = (const float*)d_in[2];
  const float* Wq    = (const float*)d_in[3];
  const float* Wc    = (const float*)d_in[4];
  const float* bc    = (const float*)d_in[5];
  const float* Wo    = (const float*)d_in[6];
  const float* bo    = (const float*)d_in[7];
  float* out = (float*)d_out;

  unsigned short* wcbp = (unsigned short*)d_ws;                   // 1 MB packed bf16 Wc
  float* resqc = (float*)((char*)d_ws + (1 << 20));               // 128 KB
  float* logit = (float*)((char*)d_ws + (1 << 20) + (1 << 17));   // 32 x 2048 f32 = 256 KB
  float* wout = out + NB * CH;                                    // final weights slot

  hipMemsetAsync(out, 0, NB * CH * sizeof(float), stream);        // zero output region
  k_resqc<<<128, 256, 0, stream>>>(query, Wq, bc, resqc);
  k_pack_wc<<<256, 256, 0, stream>>>(Wc, wcbp);
  k_logits<<<256, 1024, 0, stream>>>(ctx, wcbp, resqc, Wo, logit);
  k_weights<<<32, 256, 0, stream>>>(mask, bo, logit, wout);
  k_output<<<512, 256, 0, stream>>>(ctx, wout, out);
}

// Round 6
// 140.142 us; speedup vs baseline: 1.2222x; 1.2222x over previous
//
#include <hip/hip_runtime.h>

#define NB 32
#define LL 2048
#define CH 512
#define BQ 512
#define HH 1024
#define LDA 520   // LDS row stride (bf16): +8 pad -> measured 0 bank conflicts (r3/r4)

typedef __attribute__((ext_vector_type(8))) short bf16x8;
typedef __attribute__((ext_vector_type(16))) float f32x16;

__device__ __forceinline__ unsigned short f2bf(float x) {
  unsigned int u = __float_as_uint(x);
  u += 0x7FFFu + ((u >> 16) & 1u);   // round-to-nearest-even
  return (unsigned short)(u >> 16);
}

__device__ __forceinline__ unsigned int cvt_pk_bf16(float a, float b) {
  unsigned int r;
  asm("v_cvt_pk_bf16_f32 %0, %1, %2" : "=v"(r) : "v"(a), "v"(b));
  return r;   // lo16 = bf16(a), hi16 = bf16(b)
}

__device__ __forceinline__ float fast_tanh(float x) {
  // tanh(x) = 1 - 2/(exp2(2*log2e*x)+1); saturates correctly at +-inf
  float e = __builtin_amdgcn_exp2f(x * 2.885390081777927f);
  return 1.0f - 2.0f * __builtin_amdgcn_rcpf(e + 1.0f);
}

// ---------------- res_qc[b][h] = query[b,:]·Wq[h,:] + bc[h] ----------------
__global__ __launch_bounds__(256) void k_resqc(const float* __restrict__ query,
                                               const float* __restrict__ Wq,
                                               const float* __restrict__ bc,
                                               float* __restrict__ resqc) {
  int gid = blockIdx.x * 256 + threadIdx.x;   // 32768
  int b = gid >> 10, h = gid & 1023;
  const float4* q4 = (const float4*)(query + (size_t)b * BQ);
  const float4* w4 = (const float4*)(Wq + (size_t)h * BQ);
  float acc = 0.f;
#pragma unroll 4
  for (int i = 0; i < BQ / 4; ++i) {
    float4 a = q4[i], w = w4[i];
    acc += a.x * w.x + a.y * w.y + a.z * w.z + a.w * w.w;
  }
  resqc[gid] = acc + bc[h];
}

// ---------------- Wc f32 -> bf16, packed in MFMA B-fragment order ----------------
// wcbp[cg][ks][lane][8] : lane=(lo,hi) gets Wc[cg*32+lo][hi*8 + ks*16 .. +8]
__global__ __launch_bounds__(256) void k_pack_wc(const float* __restrict__ Wc,
                                                 unsigned short* __restrict__ wcbp) {
  int gid = blockIdx.x * 256 + threadIdx.x;   // 65536 = 32 cg * 32 ks * 64 lanes
  int lane = gid & 63, ks = (gid >> 6) & 31, cg = gid >> 11;
  int lo = lane & 31, hi = lane >> 5;
  const float4* s = (const float4*)(Wc + (size_t)(cg * 32 + lo) * CH + hi * 8 + ks * 16);
  float4 v0 = s[0], v1 = s[1];
  union { unsigned short s[8]; uint4 u; } p;
  p.s[0] = f2bf(v0.x); p.s[1] = f2bf(v0.y); p.s[2] = f2bf(v0.z); p.s[3] = f2bf(v0.w);
  p.s[4] = f2bf(v1.x); p.s[5] = f2bf(v1.y); p.s[6] = f2bf(v1.z); p.s[7] = f2bf(v1.w);
  ((uint4*)wcbp)[gid] = p.u;
}

// stage one 64x512 f32 ctx tile -> bf16 LDS buffer (512 threads, 16 float4 each)
__device__ __forceinline__ void stage_tile(const float* __restrict__ ctx,
                                           unsigned short* __restrict__ dst,
                                           int g, int t) {
  int b = g >> 5, row0 = (g & 31) << 6;
  const float4* src = (const float4*)(ctx + ((size_t)(b * LL + row0)) * CH);
#pragma unroll
  for (int i = 0; i < 16; ++i) {
    int f = i * 512 + t;
    int r = f >> 7, c4 = f & 127;
    float4 v = src[f];
    uint2 w;
    w.x = cvt_pk_bf16(v.x, v.y);
    w.y = cvt_pk_bf16(v.z, v.w);
    *(uint2*)(dst + r * LDA + c4 * 4) = w;
  }
}

// ---------------- main: logits[b][l] = sum_h Wo[h]*tanh(resqc[b][h] + ctx[b,l,:]·Wc[h,:])
// 256 persistent blocks x 512 threads (8 waves). Wave = 64 rows x 128 cols
// (acc 2x4 f32x16 = 128 AGPR; launch_bounds(512,2) -> 256-reg budget, no spill).
// 8 waves x 128 cols = full H per tile. LDS double-buffered A tile; stage(t+1)
// issued before K-loop(t). 4 tiles per block.
__global__ __launch_bounds__(512, 2) void k_logits(const float* __restrict__ ctx,
                                                   const unsigned short* __restrict__ wcbp,
                                                   const float* __restrict__ resqc,
                                                   const float* __restrict__ Wo,
                                                   float* __restrict__ logits) {
  __shared__ unsigned short Alds[2][64 * LDA];   // 2 x 66560 B
  __shared__ float lsum4[4][64];

  const int t = threadIdx.x;
  const int g0 = blockIdx.x * 4;

  if (t < 256) lsum4[t >> 6][t & 63] = 0.f;

  stage_tile(ctx, Alds[0], g0, t);
  __syncthreads();

  const int wave = t >> 6, lane = t & 63;
  const int lo = lane & 31, hi = lane >> 5;
  const int n0 = wave * 128;         // this wave's 128 cols
  const uint4* bp = (const uint4*)wcbp + (size_t)(wave * 4) * 2048 + lane;  // cg stride = 32*64 uint4
  float wo_[4];
#pragma unroll
  for (int n = 0; n < 4; ++n) wo_[n] = Wo[n0 + n * 32 + lo];

  for (int tt = 0; tt < 4; ++tt) {
    const int g = g0 + tt;
    const int b = g >> 5, row0 = (g & 31) << 6;
    const int cur = tt & 1;

    if (tt < 3) stage_tile(ctx, Alds[cur ^ 1], g + 1, t);   // overlaps with K-loop below

    const char* a0b = (const char*)(Alds[cur]) + lo * (LDA * 2) + hi * 16;

    f32x16 acc[2][4];
#pragma unroll
    for (int m = 0; m < 2; ++m)
#pragma unroll
      for (int n = 0; n < 4; ++n) acc[m][n] = (f32x16){0,0,0,0,0,0,0,0,0,0,0,0,0,0,0,0};

#pragma unroll 4
    for (int ks = 0; ks < 32; ++ks) {           // K = 512/16
      uint4 ub[4];
#pragma unroll
      for (int n = 0; n < 4; ++n) ub[n] = bp[(size_t)n * 2048 + ks * 64];
      bf16x8 fa[2];
#pragma unroll
      for (int m = 0; m < 2; ++m)
        fa[m] = *(const bf16x8*)(a0b + m * (32 * LDA * 2) + ks * 32);
#pragma unroll
      for (int m = 0; m < 2; ++m)
#pragma unroll
        for (int n = 0; n < 4; ++n) {
          bf16x8 fb;
          __builtin_memcpy(&fb, &ub[n], 16);
          acc[m][n] = __builtin_amdgcn_mfma_f32_32x32x16_bf16(fa[m], fb, acc[m][n], 0, 0, 0);
        }
    }

    // epilogue: tanh + Wo-weighted col-sum -> 32 partials/lane, transpose-reduce
    float q_[4];
#pragma unroll
    for (int n = 0; n < 4; ++n) q_[n] = resqc[b * HH + n0 + n * 32 + lo];
    float v[32];
#pragma unroll
    for (int m = 0; m < 2; ++m)
#pragma unroll
      for (int r = 0; r < 16; ++r) {
        float s = 0.f;
#pragma unroll
        for (int n = 0; n < 4; ++n) s += wo_[n] * fast_tanh(acc[m][n][r] + q_[n]);
        v[m * 16 + r] = s;
      }
    // transpose-reduce: after 5 levels lane lo holds the full 32-lane sum of
    // value index lo (31 shfl instead of 160).
#pragma unroll
    for (int s = 16; s >= 1; s >>= 1) {
#pragma unroll
      for (int i = 0; i < s; ++i) {
        float a = v[i], c = v[i + s];
        float keep = (lo & s) ? c : a;
        float send = (lo & s) ? a : c;
        v[i] = keep + __shfl_xor(send, s, 64);
      }
    }
    int rr = lo & 15;
    int row = ((lo < 16) ? 0 : 32) + (rr & 3) + 8 * (rr >> 2) + 4 * hi;  // C/D row map
    atomicAdd(&lsum4[tt][row], v[0]);

    __syncthreads();
    if (t < 64) logits[(size_t)b * LL + row0 + t] = lsum4[tt][t];
  }
}

// ---------------- weights: mask*exp(logit+bo), normalize over L ----------------
__global__ __launch_bounds__(256) void k_weights(const float* __restrict__ mask,
                                                 const float* __restrict__ bo,
                                                 const float* __restrict__ logit,
                                                 float* __restrict__ wout) {
  __shared__ float red[4];
  int b = blockIdx.x, t = threadIdx.x;
  float bov = bo[0];
  float w[8];
  float s = 0.f;
#pragma unroll
  for (int i = 0; i < 8; ++i) {
    int l = t + 256 * i;
    float e = mask[b * LL + l] * __expf(logit[b * LL + l] + bov);
    w[i] = e; s += e;
  }
#pragma unroll
  for (int m = 32; m >= 1; m >>= 1) s += __shfl_xor(s, m, 64);
  int wave = t >> 6, lane = t & 63;
  if (lane == 0) red[wave] = s;
  __syncthreads();
  float inv = 1.0f / (red[0] + red[1] + red[2] + red[3] + 1e-5f);
#pragma unroll
  for (int i = 0; i < 8; ++i) wout[b * LL + t + 256 * i] = w[i] * inv;
}

// ---------------- output[b][c] = sum_l weights[b][l] * ctx[b][l][c] ----------------
__global__ __launch_bounds__(256) void k_output(const float* __restrict__ ctx,
                                                const float* __restrict__ weights,
                                                float* __restrict__ out) {
  __shared__ float wl[128];
  int bid = blockIdx.x;            // 512 = 32 b * 16 chunks
  int b = bid >> 4, chunk = bid & 15;
  int t = threadIdx.x;
  int l0 = chunk * 128;
  if (t < 128) wl[t] = weights[b * LL + l0 + t];
  __syncthreads();
  const float2* c2 = (const float2*)(ctx + ((size_t)(b * LL + l0)) * CH) + t;
  float ax = 0.f, ay = 0.f;
#pragma unroll 4
  for (int l = 0; l < 128; ++l) {
    float wv = wl[l];
    float2 v = c2[(size_t)l * (CH / 2)];
    ax += wv * v.x; ay += wv * v.y;
  }
  atomicAdd(&out[b * CH + 2 * t], ax);
  atomicAdd(&out[b * CH + 2 * t + 1], ay);
}

extern "C" void kernel_launch(void* const* d_in, const int* in_sizes, int n_in,
                              void* d_out, int out_size, void* d_ws, size_t ws_size,
                              hipStream_t stream) {
  const float* query = (const float*)d_in[0];
  const float* ctx   = (const float*)d_in[1];
  const float* mask  = (const float*)d_in[2];
  const float* Wq    = (const float*)d_in[3];
  const float* Wc    = (const float*)d_in[4];
  const float* bc    = (const float*)d_in[5];
  const float* Wo    = (const float*)d_in[6];
  const float* bo    = (const float*)d_in[7];
  float* out = (float*)d_out;

  unsigned short* wcbp = (unsigned short*)d_ws;                   // 1 MB packed bf16 Wc
  float* resqc = (float*)((char*)d_ws + (1 << 20));               // 128 KB
  float* logit = (float*)((char*)d_ws + (1 << 20) + (1 << 17));   // 32 x 2048 f32 = 256 KB
  float* wout = out + NB * CH;                                    // final weights slot

  hipMemsetAsync(out, 0, NB * CH * sizeof(float), stream);        // zero output region
  k_resqc<<<128, 256, 0, stream>>>(query, Wq, bc, resqc);
  k_pack_wc<<<256, 256, 0, stream>>>(Wc, wcbp);
  k_logits<<<256, 512, 0, stream>>>(ctx, wcbp, resqc, Wo, logit);
  k_weights<<<32, 256, 0, stream>>>(mask, bo, logit, wout);
  k_output<<<512, 256, 0, stream>>>(ctx, wout, out);
}